// Round 1
// baseline (319.705 us; speedup 1.0000x reference)
//
#include <hip/hip_runtime.h>

// FGPillarMaxPooling on MI355X (gfx950) — bin-then-gather restructure.
//
// Previous best (253 µs) = 139 µs hipMemsetAsync(128 MiB) + 113 µs scatter
// kernel bound by 25.6M global atomicMax ops. This version:
//   1) pass_count:   per-point cell histogram (800k int atomics, low contention)
//   2) pass_scan:    exclusive scan of 1M cell counts -> per-cell base offsets
//                    (block scan + one global atomicAdd per block; cell order
//                    within a 1024-cell chunk is preserved -> records stay
//                    nearly sequential for the gather pass)
//   3) pass_scatter: recompute cell, atomicAdd per-cell cursor, write compact
//                    32B record {feat4 | dx,dy,dz,pad}
//   4) pass_pool:    one lane per (cell,channel): loop the cell's records,
//                    h = g @ W, relu, max. Writes EVERY output cell exactly
//                    once (empty -> 0), so no output memset is needed at all.
// Max is order-independent -> result is deterministic despite atomic slot
// assignment order varying.
//
// Fallback: if ws_size < ~34 MB, use the previous memset+atomicMax path.

#define GW 512
#define GH 512
#define COUT 32

__device__ __forceinline__ int batch_of(int p, const int* __restrict__ cnt, int B) {
    int b = 0, acc = 0;
    for (int k = 0; k < B; ++k) { acc += cnt[k]; b += (p >= acc) ? 1 : 0; }
    return b;
}

__device__ __forceinline__ void cell_of(float x, float y, int& px, int& py) {
    // keep IEEE division to match the reference's floor decisions
    px = (int)floorf((x - (-51.2f)) / 0.2f);
    py = (int)floorf((y - (-51.2f)) / 0.2f);
    px = min(max(px, 0), GW - 1);
    py = min(max(py, 0), GH - 1);
}

__global__ __launch_bounds__(256) void pass_count(
    const float* __restrict__ xyz, const int* __restrict__ cnt,
    unsigned* __restrict__ counts, int N, int B)
{
    int p = blockIdx.x * 256 + threadIdx.x;
    if (p >= N) return;
    float x = xyz[3 * p + 0];
    float y = xyz[3 * p + 1];
    int px, py; cell_of(x, y, px, py);
    int b = batch_of(p, cnt, B);
    unsigned seg = (unsigned)b * (GH * GW) + (unsigned)py * GW + (unsigned)px;
    atomicAdd(&counts[seg], 1u);
}

__global__ __launch_bounds__(256) void pass_scan(
    const unsigned* __restrict__ counts, unsigned* __restrict__ cursor,
    unsigned* __restrict__ gcur, int ncells)
{
    __shared__ unsigned waveOff[4];
    __shared__ unsigned blockBase;
    int tid = threadIdx.x;
    int base = (blockIdx.x * 256 + tid) * 4;

    uint4 cv = make_uint4(0u, 0u, 0u, 0u);
    if (base + 3 < ncells) {
        cv = *(const uint4*)(counts + base);
    } else if (base < ncells) {
        cv.x = counts[base];
        if (base + 1 < ncells) cv.y = counts[base + 1];
        if (base + 2 < ncells) cv.z = counts[base + 2];
    }
    unsigned lsum = cv.x + cv.y + cv.z + cv.w;

    // inclusive scan across the 64-lane wave
    unsigned s = lsum;
    int lane = tid & 63;
    #pragma unroll
    for (int d = 1; d < 64; d <<= 1) {
        unsigned t = __shfl_up(s, d, 64);
        if (lane >= d) s += t;
    }
    int wv = tid >> 6;
    if (lane == 63) waveOff[wv] = s;
    __syncthreads();
    if (tid == 0) {
        unsigned w0 = waveOff[0], w1 = waveOff[1], w2 = waveOff[2], w3 = waveOff[3];
        blockBase = atomicAdd(gcur, w0 + w1 + w2 + w3);
        waveOff[0] = 0; waveOff[1] = w0; waveOff[2] = w0 + w1; waveOff[3] = w0 + w1 + w2;
    }
    __syncthreads();

    unsigned start = blockBase + waveOff[wv] + (s - lsum);  // exclusive base for this thread
    uint4 o;
    o.x = start;
    o.y = o.x + cv.x;
    o.z = o.y + cv.y;
    o.w = o.z + cv.z;
    if (base + 3 < ncells) {
        *(uint4*)(cursor + base) = o;
    } else if (base < ncells) {
        cursor[base] = o.x;
        if (base + 1 < ncells) cursor[base + 1] = o.y;
        if (base + 2 < ncells) cursor[base + 2] = o.z;
    }
}

__global__ __launch_bounds__(256) void pass_scatter(
    const float* __restrict__ xyz, const int* __restrict__ cnt,
    const float4* __restrict__ feat,
    unsigned* __restrict__ cursor, float4* __restrict__ records,
    int N, int B)
{
    int p = blockIdx.x * 256 + threadIdx.x;
    if (p >= N) return;
    float x = xyz[3 * p + 0];
    float y = xyz[3 * p + 1];
    float z = xyz[3 * p + 2];
    int px, py; cell_of(x, y, px, py);
    int b = batch_of(p, cnt, B);
    float cx = ((float)px + 0.5f) * 0.2f + (-51.2f);
    float cy = ((float)py + 0.5f) * 0.2f + (-51.2f);
    float4 f = feat[p];
    unsigned seg = (unsigned)b * (GH * GW) + (unsigned)py * GW + (unsigned)px;
    unsigned slot = atomicAdd(&cursor[seg], 1u);   // after this pass: cursor[seg] == end
    records[(size_t)2 * slot + 0] = f;
    records[(size_t)2 * slot + 1] = make_float4(x - cx, y - cy, z + 1.0f, 0.0f);
}

__global__ __launch_bounds__(256) void pass_pool(
    const unsigned* __restrict__ counts, const unsigned* __restrict__ cursor,
    const float* __restrict__ W, const float4* __restrict__ records,
    float* __restrict__ out, int ncells)
{
    int tid = threadIdx.x;
    int cell = blockIdx.x * 8 + (tid >> 5);
    int c = tid & 31;
    if (cell >= ncells) return;

    // per-lane weight column (896B total, L1-resident after first block)
    float w0 = W[0 * COUT + c], w1 = W[1 * COUT + c], w2 = W[2 * COUT + c];
    float w3 = W[3 * COUT + c], w4 = W[4 * COUT + c], w5 = W[5 * COUT + c];
    float w6 = W[6 * COUT + c];

    unsigned end = cursor[cell];
    unsigned num = counts[cell];
    unsigned i = end - num;

    float best = 0.0f;  // relu(h) >= 0 and empty cells map to 0
    for (; i < end; ++i) {
        float4 f = records[(size_t)2 * i + 0];
        float4 g = records[(size_t)2 * i + 1];
        float h = f.x * w0 + f.y * w1 + f.z * w2 + f.w * w3
                + g.x * w4 + g.y * w5 + g.z * w6;
        best = fmaxf(best, h);
    }
    out[(size_t)cell * COUT + c] = best;  // fully coalesced, every cell written
}

// ---------------- fallback (previous best): memset + atomicMax scatter -------

#define PTS_PER_BLOCK 8

__global__ __launch_bounds__(256) void pillar_fwd(
    const float* __restrict__ xyz, const int* __restrict__ cnt,
    const float4* __restrict__ feat, const float* __restrict__ W,
    unsigned int* __restrict__ out, int N, int B)
{
    __shared__ float sW[7 * COUT];
    int tid = threadIdx.x;
    if (tid < 7 * COUT) sW[tid] = W[tid];
    __syncthreads();

    int p = blockIdx.x * PTS_PER_BLOCK + (tid >> 5);
    int c = tid & 31;
    if (p >= N) return;

    float x = xyz[3 * p + 0];
    float y = xyz[3 * p + 1];
    float z = xyz[3 * p + 2];
    int b = batch_of(p, cnt, B);
    int px, py; cell_of(x, y, px, py);
    float cx = ((float)px + 0.5f) * 0.2f + (-51.2f);
    float cy = ((float)py + 0.5f) * 0.2f + (-51.2f);
    float4 f = feat[p];
    float h = f.x * sW[0 * COUT + c] + f.y * sW[1 * COUT + c]
            + f.z * sW[2 * COUT + c] + f.w * sW[3 * COUT + c]
            + (x - cx) * sW[4 * COUT + c] + (y - cy) * sW[5 * COUT + c]
            + (z + 1.0f) * sW[6 * COUT + c];
    h = fmaxf(h, 0.0f);
    unsigned seg = (unsigned)b * (GH * GW) + (unsigned)py * GW + (unsigned)px;
    atomicMax(out + (size_t)seg * COUT + c, __float_as_uint(h));
}

extern "C" void kernel_launch(void* const* d_in, const int* in_sizes, int n_in,
                              void* d_out, int out_size, void* d_ws, size_t ws_size,
                              hipStream_t stream) {
    const float*  xyz  = (const float*)d_in[0];
    const int*    cnt  = (const int*)d_in[1];
    const float4* feat = (const float4*)d_in[2];
    const float*  W    = (const float*)d_in[3];

    int N = in_sizes[0] / 3;
    int B = in_sizes[1];
    int ncells = B * GH * GW;

    // workspace layout: [gcur(256B pad)] [counts ncells*4] [cursor ncells*4] [records N*32]
    size_t offCounts  = 256;
    size_t offCursor  = offCounts + (size_t)ncells * 4;
    size_t offRecords = (offCursor + (size_t)ncells * 4 + 255) & ~(size_t)255;
    size_t needed     = offRecords + (size_t)N * 32;

    if (ws_size >= needed) {
        char* ws = (char*)d_ws;
        unsigned* gcur    = (unsigned*)ws;
        unsigned* counts  = (unsigned*)(ws + offCounts);
        unsigned* cursor  = (unsigned*)(ws + offCursor);
        float4*   records = (float4*)(ws + offRecords);

        // zero gcur + counts only (8.4 MB >> 134 MB output memset it replaces)
        hipMemsetAsync(ws, 0, offCursor, stream);

        int gpts = (N + 255) / 256;
        pass_count<<<gpts, 256, 0, stream>>>(xyz, cnt, counts, N, B);
        pass_scan<<<(ncells + 1023) / 1024, 256, 0, stream>>>(counts, cursor, gcur, ncells);
        pass_scatter<<<gpts, 256, 0, stream>>>(xyz, cnt, feat, cursor, records, N, B);
        pass_pool<<<(ncells + 7) / 8, 256, 0, stream>>>(counts, cursor, W, records,
                                                        (float*)d_out, ncells);
    } else {
        // fallback: previous best path
        hipMemsetAsync(d_out, 0, (size_t)out_size * sizeof(float), stream);
        int grid = (N + PTS_PER_BLOCK - 1) / PTS_PER_BLOCK;
        pillar_fwd<<<grid, 256, 0, stream>>>(xyz, cnt, feat, W,
                                             (unsigned int*)d_out, N, B);
    }
}

// Round 2
// 260.084 us; speedup vs baseline: 1.2292x; 1.2292x over previous
//
#include <hip/hip_runtime.h>

// FGPillarMaxPooling on MI355X (gfx950) — single-pass atomicMax, v3.
//
// R1 lesson: bin-then-gather (4 passes) lost to its own constant factors
// (random 32B record scatter + 1.65 TB/s pool write) -> 320 µs. Reverted.
//
// v3 = baseline atomic path + two targeted fixes:
//  1) Replace hipMemsetAsync(128 MiB) — measured at only 0.96 TB/s (139 µs)
//     under graph capture — with a grid-stride uint4 zero kernel (~35 µs).
//  2) Skip identity atomics: out is zero-initialized and relu(h) == 0 for
//     ~50% of (point,channel) pairs; atomicMax(p, 0) is a no-op. Predicating
//     on h > 0 halves the L2 atomic op count (25.6M -> ~12.8M). The 113 µs
//     kernel is atomic-throughput-bound (25.6M / ~300G atomics/s ≈ 85 µs),
//     so this should scale dur accordingly.

#define GW 512
#define GH 512
#define COUT 32
#define PTS_PER_BLOCK 8   // 256 threads / 32 channels

__global__ __launch_bounds__(256) void zero_out(uint4* __restrict__ out, int n4)
{
    int stride = gridDim.x * 256;
    for (int i = blockIdx.x * 256 + threadIdx.x; i < n4; i += stride)
        out[i] = make_uint4(0u, 0u, 0u, 0u);
}

__global__ __launch_bounds__(256) void pillar_fwd(
    const float* __restrict__ xyz,        // (N,3)
    const int*   __restrict__ cnt,        // (B,)
    const float4* __restrict__ feat,      // (N,4) as float4
    const float* __restrict__ W,          // (7,32) row-major
    unsigned int* __restrict__ out,       // (B*GH*GW, 32) float bits
    int N, int B)
{
    __shared__ float sW[7 * COUT];
    int tid = threadIdx.x;
    if (tid < 7 * COUT) sW[tid] = W[tid];
    __syncthreads();

    int p = blockIdx.x * PTS_PER_BLOCK + (tid >> 5);
    int c = tid & 31;
    if (p >= N) return;

    float x = xyz[3 * p + 0];
    float y = xyz[3 * p + 1];
    float z = xyz[3 * p + 2];

    // batch index from prefix sums of cnt (B small; uniform loads broadcast)
    int b = 0, acc = 0;
    for (int k = 0; k < B; ++k) {
        acc += cnt[k];
        b += (p >= acc) ? 1 : 0;
    }

    // pillar cell — keep IEEE division to match the reference's floor decisions
    int px = (int)floorf((x - (-51.2f)) / 0.2f);
    int py = (int)floorf((y - (-51.2f)) / 0.2f);
    px = min(max(px, 0), GW - 1);
    py = min(max(py, 0), GH - 1);

    float cx = ((float)px + 0.5f) * 0.2f + (-51.2f);
    float cy = ((float)py + 0.5f) * 0.2f + (-51.2f);
    // cz = 0.5*(-5.0 + 3.0) = -1.0  ->  z - cz = z + 1.0
    float g4 = x - cx;
    float g5 = y - cy;
    float g6 = z + 1.0f;

    float4 f = feat[p];

    float h = f.x * sW[0 * COUT + c]
            + f.y * sW[1 * COUT + c]
            + f.z * sW[2 * COUT + c]
            + f.w * sW[3 * COUT + c]
            + g4  * sW[4 * COUT + c]
            + g5  * sW[5 * COUT + c]
            + g6  * sW[6 * COUT + c];

    // out is zero-initialized and atomicMax(p, 0) is an identity op:
    // only lanes with h > 0 need to touch memory (~50% on this data).
    if (h > 0.0f) {
        unsigned seg = (unsigned)b * (GH * GW) + (unsigned)py * GW + (unsigned)px;
        atomicMax(out + (size_t)seg * COUT + c, __float_as_uint(h));
    }
}

extern "C" void kernel_launch(void* const* d_in, const int* in_sizes, int n_in,
                              void* d_out, int out_size, void* d_ws, size_t ws_size,
                              hipStream_t stream) {
    const float*  xyz  = (const float*)d_in[0];
    const int*    cnt  = (const int*)d_in[1];
    const float4* feat = (const float4*)d_in[2];
    const float*  W    = (const float*)d_in[3];
    unsigned int* out  = (unsigned int*)d_out;

    int N = in_sizes[0] / 3;
    int B = in_sizes[1];

    // Output is re-poisoned to 0xAA before every timed launch — zero it with
    // a full-BW streaming kernel (hipMemsetAsync measured only 0.96 TB/s).
    int n4 = out_size / 4;                 // out_size = #floats, divisible by 4
    zero_out<<<2048, 256, 0, stream>>>((uint4*)d_out, n4);

    int grid = (N + PTS_PER_BLOCK - 1) / PTS_PER_BLOCK;
    pillar_fwd<<<grid, 256, 0, stream>>>(xyz, cnt, feat, W, out, N, B);
}